// Round 3
// baseline (12053.293 us; speedup 1.0000x reference)
//
#include <hip/hip_runtime.h>
#include <stdint.h>
#include <math.h>

#define SEQ   4096
#define INDIM 1024
#define HID   1024
#define GCOLS 4096   // 4 gates * HID

// =================== Phase 1: Xp[t][g*1024+j] = bias_g[j] + sum_k batch[t][k]*Wg[k][j]
// fp32 vector GEMM, 128x128 tile, 256 threads, 8x8 per thread, BK=8.
__global__ __launch_bounds__(256) void xproj_gemm(
    const float* __restrict__ batch,
    const float* __restrict__ Wf, const float* __restrict__ Bf,
    const float* __restrict__ Wi, const float* __restrict__ Bi,
    const float* __restrict__ Wm, const float* __restrict__ Bm,
    const float* __restrict__ Wo, const float* __restrict__ Bo,
    float* __restrict__ Xp)
{
    __shared__ float As[8][128];
    __shared__ float Bs[8][128];

    const int bx = blockIdx.x;          // 0..31 : col block (gate = bx>>3)
    const int by = blockIdx.y;          // 0..31 : row block
    const int gate = bx >> 3;
    const int cb = (bx & 7) * 128;      // col base within gate

    const float* W; const float* Bv;
    if      (gate == 0) { W = Wf; Bv = Bf; }
    else if (gate == 1) { W = Wi; Bv = Bi; }
    else if (gate == 2) { W = Wm; Bv = Bm; }
    else                { W = Wo; Bv = Bo; }

    const int t  = threadIdx.x;
    const int tx = t & 15;
    const int ty = t >> 4;
    const int arow = t >> 1;            // 0..127
    const int akc  = (t & 1) * 4;       // 0 or 4
    const int bkk  = t >> 5;            // 0..7
    const int bc4  = (t & 31) * 4;      // 0..124

    float acc[8][8];
#pragma unroll
    for (int r = 0; r < 8; ++r)
#pragma unroll
        for (int c = 0; c < 8; ++c) acc[r][c] = 0.f;

    const float* aptr = batch + (size_t)(by * 128 + arow) * INDIM + akc;
    const float* bptr = W + (size_t)bkk * HID + cb + bc4;

    for (int k0 = 0; k0 < INDIM; k0 += 8) {
        float4 av = *(const float4*)(aptr + k0);
        float4 bv = *(const float4*)(bptr + (size_t)k0 * HID);
        __syncthreads();   // previous tile fully consumed
        As[akc + 0][arow] = av.x;
        As[akc + 1][arow] = av.y;
        As[akc + 2][arow] = av.z;
        As[akc + 3][arow] = av.w;
        *(float4*)&Bs[bkk][bc4] = bv;
        __syncthreads();
#pragma unroll
        for (int kk = 0; kk < 8; ++kk) {
            float a[8], b[8];
            *(float4*)&a[0] = *(const float4*)&As[kk][ty * 8];
            *(float4*)&a[4] = *(const float4*)&As[kk][ty * 8 + 4];
            *(float4*)&b[0] = *(const float4*)&Bs[kk][tx * 8];
            *(float4*)&b[4] = *(const float4*)&Bs[kk][tx * 8 + 4];
#pragma unroll
            for (int r = 0; r < 8; ++r)
#pragma unroll
                for (int c = 0; c < 8; ++c)
                    acc[r][c] = fmaf(a[r], b[c], acc[r][c]);
        }
    }

    float bias[8];
    *(float4*)&bias[0] = *(const float4*)(Bv + cb + tx * 8);
    *(float4*)&bias[4] = *(const float4*)(Bv + cb + tx * 8 + 4);

#pragma unroll
    for (int r = 0; r < 8; ++r) {
        float4 o0, o1;
        o0.x = acc[r][0] + bias[0]; o0.y = acc[r][1] + bias[1];
        o0.z = acc[r][2] + bias[2]; o0.w = acc[r][3] + bias[3];
        o1.x = acc[r][4] + bias[4]; o1.y = acc[r][5] + bias[5];
        o1.z = acc[r][6] + bias[6]; o1.w = acc[r][7] + bias[7];
        float* dst = Xp + (size_t)(by * 128 + ty * 8 + r) * GCOLS + gate * HID + cb + tx * 8;
        *(float4*)(dst)     = o0;
        *(float4*)(dst + 4) = o1;
    }
}

// =================== Phase 2: persistent recurrence, 256 blocks x 256 threads.
// Plain launch (NO cooperative, NO grid.sync): we only need co-residency,
// guaranteed by grid=256 <= 256 CUs at __launch_bounds__(256,1) (~100 VGPR
// -> >=2 blocks/CU would fit, so every block is resident immediately).
// Block b owns h indices 4b..4b+3. Wave w = gate (0=f,1=i,2=m,3=o) holds
// W_h[k][4b..4b+3] in VGPRs (64 regs). h published per-value as packed
// (tag<<32)|float_bits, device-scope relaxed atomics; the tag IS the sync.
// Double-buffered h => overwrite-safe (any block lags <= 1 step: a writer
// reaches buffer p at step s+2 only after observing ALL tag-(s+2) values in
// buffer 1-p, each published after its block's __syncthreads, i.e. after
// that block finished READING buffer p at step s).
__device__ __forceinline__ int swzg(int g) { return g ^ ((g >> 3) & 7); }  // 16B-granule XOR swizzle

__global__ __launch_bounds__(256, 1) void lstm_rec(
    const float* __restrict__ Wf, const float* __restrict__ Wi,
    const float* __restrict__ Wm, const float* __restrict__ Wo,
    const float* __restrict__ Xp,
    unsigned long long* __restrict__ hb,   // 2 x 1024 packed (tag,val)
    float* __restrict__ out)
{
    const int b = blockIdx.x;      // 0..255
    const int t = threadIdx.x;     // 0..255
    const int w = t >> 6;          // wave = gate index
    const int l = t & 63;          // lane
    const int j4 = b * 4;

    __shared__ float hsw[1024];    // swizzled h staging
    __shared__ float gsum[16];     // [gate*4 + c]

    // publish h^(0) = 0 with tag 1 into buffer 0 FIRST (before the slow
    // weight fill) so early-arriving blocks don't burn poll budget on us.
    if (t < 4)
        __hip_atomic_store(&hb[j4 + t], 1ull << 32,
                           __ATOMIC_RELAXED, __HIP_MEMORY_SCOPE_AGENT);

    const float* W = (w == 0) ? Wf : (w == 1) ? Wi : (w == 2) ? Wm : Wo;

    // Load this lane's W_h fragment: k = 16l..16l+15, cols j4..j4+3 (contiguous float4)
    float wr[16][4];
#pragma unroll
    for (int i = 0; i < 16; ++i) {
        float4 v = *(const float4*)(W + (size_t)(INDIM + 16 * l + i) * HID + j4);
        wr[i][0] = v.x; wr[i][1] = v.y; wr[i][2] = v.z; wr[i][3] = v.w;
    }

    // spin-load assignment: wave w lane l covers k = w*256 + 4l .. +3
    const int kq = w * 256 + l * 4;
    const int wgr = swzg(w * 64 + l);          // staging write granule
    const int rg0 = swzg(4 * l + 0), rg1 = swzg(4 * l + 1);
    const int rg2 = swzg(4 * l + 2), rg3 = swzg(4 * l + 3);

    float cst = 0.f;               // cell state (lanes t<4 of wave 0)
    int budget = 1 << 21;          // cumulative poll budget: bug => wrong answer, not hang

    for (int s = 0; s < SEQ; ++s) {
        const unsigned long long* src = hb + (size_t)(s & 1) * 1024;
        unsigned long long*       dst = hb + (size_t)((s + 1) & 1) * 1024;
        const unsigned int tg = (unsigned int)(s + 1);

        // prefetch Xp (independent of h): wave w lanes 0..3 -> gate w, col j4+l
        float xp = 0.f;
        if (l < 4) xp = Xp[(size_t)s * GCOLS + w * HID + j4 + l];

        // spin until our 4 h values carry this step's tag
        unsigned long long v0, v1, v2, v3;
        for (;;) {
            v0 = __hip_atomic_load(&src[kq + 0], __ATOMIC_RELAXED, __HIP_MEMORY_SCOPE_AGENT);
            v1 = __hip_atomic_load(&src[kq + 1], __ATOMIC_RELAXED, __HIP_MEMORY_SCOPE_AGENT);
            v2 = __hip_atomic_load(&src[kq + 2], __ATOMIC_RELAXED, __HIP_MEMORY_SCOPE_AGENT);
            v3 = __hip_atomic_load(&src[kq + 3], __ATOMIC_RELAXED, __HIP_MEMORY_SCOPE_AGENT);
            int ok = ((unsigned int)(v0 >> 32) == tg) & ((unsigned int)(v1 >> 32) == tg) &
                     ((unsigned int)(v2 >> 32) == tg) & ((unsigned int)(v3 >> 32) == tg);
            if (__all(ok)) break;
            if (--budget < 0) break;
        }

        // stage to swizzled LDS
        float4 hv;
        hv.x = __uint_as_float((unsigned int)v0);
        hv.y = __uint_as_float((unsigned int)v1);
        hv.z = __uint_as_float((unsigned int)v2);
        hv.w = __uint_as_float((unsigned int)v3);
        *(float4*)&hsw[4 * wgr] = hv;
        __syncthreads();   // (A) h staged

        // MAC: 16 k-values x 4 columns against register weights
        float h[16];
        *(float4*)&h[0]  = *(const float4*)&hsw[4 * rg0];
        *(float4*)&h[4]  = *(const float4*)&hsw[4 * rg1];
        *(float4*)&h[8]  = *(const float4*)&hsw[4 * rg2];
        *(float4*)&h[12] = *(const float4*)&hsw[4 * rg3];
        float a0 = 0.f, a1 = 0.f, a2 = 0.f, a3 = 0.f;
#pragma unroll
        for (int i = 0; i < 16; ++i) {
            a0 = fmaf(h[i], wr[i][0], a0);
            a1 = fmaf(h[i], wr[i][1], a1);
            a2 = fmaf(h[i], wr[i][2], a2);
            a3 = fmaf(h[i], wr[i][3], a3);
        }

        // ---- reduction: fold 4 col-sums -> 1 value/lane (2+1 shfl), then
        // 4-step butterfly. 7 cross-lane ops total (was 24).
        // After fold: lane l owns column (l&3).
        const bool b0 = (l & 1) != 0;
        float s1 = b0 ? a0 : a1;          // value I give up at mask 1
        float r1 = __shfl_xor(s1, 1, 64);
        float x  = (b0 ? a1 : a0) + r1;   // col (l&1)
        float s2 = b0 ? a2 : a3;
        float r2 = __shfl_xor(s2, 1, 64);
        float y  = (b0 ? a3 : a2) + r2;   // col (l&1)+2
        const bool b1 = (l & 2) != 0;
        float s3 = b1 ? x : y;            // give up the one I don't keep
        float r3 = __shfl_xor(s3, 2, 64);
        float z  = (b1 ? y : x) + r3;     // col (l&3), summed over lanes {l^0..l^3}
#pragma unroll
        for (int m = 4; m < 64; m <<= 1) z += __shfl_xor(z, m, 64);

        if (l < 4) gsum[w * 4 + l] = z + xp;   // lane l holds col l&3 == l
        __syncthreads();   // (B) gate sums ready

        if (t < 4) {       // wave 0 lanes 0..3: c = t
            float pf = gsum[0 + t], pi = gsum[4 + t], pm = gsum[8 + t], po = gsum[12 + t];
            float fg = 1.f / (1.f + expf(-pf));
            float ig = 1.f / (1.f + expf(-pi));
            float mg = tanhf(pm);
            float og = 1.f / (1.f + expf(-po));
            cst = fg * cst + ig * mg;
            float hv2 = og * tanhf(cst);
            out[(size_t)s * HID + j4 + t] = hv2;
            unsigned long long pk = ((unsigned long long)(tg + 1) << 32) |
                                    (unsigned long long)__float_as_uint(hv2);
            __hip_atomic_store(&dst[j4 + t], pk, __ATOMIC_RELAXED, __HIP_MEMORY_SCOPE_AGENT);
        }
        // no extra barrier needed: next iter's hsw writes happen after (B);
        // gsum is rewritten only after next iter's (A).
    }
}

extern "C" void kernel_launch(void* const* d_in, const int* in_sizes, int n_in,
                              void* d_out, int out_size, void* d_ws, size_t ws_size,
                              hipStream_t stream) {
    const float* batch = (const float*)d_in[0];
    const float* Wf = (const float*)d_in[1]; const float* Bf = (const float*)d_in[2];
    const float* Wi = (const float*)d_in[3]; const float* Bi = (const float*)d_in[4];
    const float* Wm = (const float*)d_in[5]; const float* Bm = (const float*)d_in[6];
    const float* Wo = (const float*)d_in[7]; const float* Bo = (const float*)d_in[8];
    float* out = (float*)d_out;

    float* Xp = (float*)d_ws;                                   // 64 MB
    unsigned long long* hb =
        (unsigned long long*)((char*)d_ws + (size_t)SEQ * GCOLS * sizeof(float)); // 16 KB

    xproj_gemm<<<dim3(32, 32), 256, 0, stream>>>(batch, Wf, Bf, Wi, Bi, Wm, Bm, Wo, Bo, Xp);

    // Plain launch: capture-safe; co-residency by construction (see comment above).
    lstm_rec<<<dim3(256), 256, 0, stream>>>(Wf, Wi, Wm, Wo, Xp, hb, out);
}